// Round 3
// baseline (223.378 us; speedup 1.0000x reference)
//
#include <hip/hip_runtime.h>

// MicrotubuleDynamicsModel fused forward (single kernel).
//   x = relu(q @ Win^T + bin)
//   3x: x += relu( A @ x @ Wg[l]^T + bg[l] )    A = normalized GCN adjacency (closed form)
//   y = relu(x @ Wd1^T + bd1); out = y @ Wd2^T + bd2
// Block = 4 samples x 8 waves (wave = (sample, 32-node half)). All matmuls as
// hT = W * xT on v_mfma_f32_32x32x16_bf16, 3-way bf16 split (h/m/l), 6 passes
// -> ~2^-24 per-product error. Residual x in registers (D-frag layout);
// fp32 mirror in LDS for the sparse gather; W staged 64 rows at a time.

#define STRF 132   // fp32 LDS row stride for xs (528B: 16B-aligned, odd window stride)
#define STRW 136   // bf16 LDS row stride for W (272B: 16B-aligned, window stride 17)

typedef __attribute__((ext_vector_type(2)))  float  f32x2;
typedef __attribute__((ext_vector_type(4)))  float  f32x4;
typedef __attribute__((ext_vector_type(16))) float  f32x16;
typedef __attribute__((ext_vector_type(8)))  __bf16 bf16x8;

#define MFMA(a, b, c) __builtin_amdgcn_mfma_f32_32x32x16_bf16((a), (b), (c), 0, 0, 0)

// 6 passes: hh + hm + mh + mm + hl + lh  (dropped: ml,lm ~2^-24, ll ~2^-32)
#define PASS6(acc, wh, wm, wl, bh, bm, bl)                              \
    acc = MFMA(wh, bh, acc); acc = MFMA(wh, bm, acc);                   \
    acc = MFMA(wm, bh, acc); acc = MFMA(wm, bm, acc);                   \
    acc = MFMA(wh, bl, acc); acc = MFMA(wl, bh, acc);

// split 8 fp32 (two f32x4) into three bf16x8 fragments
__device__ __forceinline__ void split8(const f32x4 a0, const f32x4 a1,
                                       bf16x8 &h, bf16x8 &m, bf16x8 &l) {
    #pragma unroll
    for (int e = 0; e < 4; ++e) {
        {
            const float f = a0[e];
            const __bf16 hh = (__bf16)f;  const float r1 = f - (float)hh;
            const __bf16 mm = (__bf16)r1; const float r2 = r1 - (float)mm;
            h[e] = hh; m[e] = mm; l[e] = (__bf16)r2;
        }
        {
            const float f = a1[e];
            const __bf16 hh = (__bf16)f;  const float r1 = f - (float)hh;
            const __bf16 mm = (__bf16)r1; const float r2 = r1 - (float)mm;
            h[4+e] = hh; m[4+e] = mm; l[4+e] = (__bf16)r2;
        }
    }
}

__global__ __launch_bounds__(512, 2) void mt_fwd(
    const float* __restrict__ q,   const float* __restrict__ Win, const float* __restrict__ bin,
    const float* __restrict__ Wg,  const float* __restrict__ bg,
    const float* __restrict__ Wd1, const float* __restrict__ bd1,
    const float* __restrict__ Wd2, const float* __restrict__ bd2,
    float* __restrict__ out)
{
    __shared__ __attribute__((aligned(16))) float  xs[4 * 52 * STRF];  // 109824 B
    __shared__ __attribute__((aligned(16))) __bf16 Wh[64 * STRW];      // 17408 B
    __shared__ __attribute__((aligned(16))) __bf16 Wm[64 * STRW];      // 17408 B
    __shared__ __attribute__((aligned(16))) __bf16 Wl[64 * STRW];      // 17408 B

    const int t    = threadIdx.x;
    const int w    = t >> 6;          // wave 0..7
    const int l    = t & 63;
    const int s    = w >> 1;          // sample-in-block 0..3
    const int nt   = w & 1;           // node-tile (0: nodes 0..31, 1: 32..63)
    const int lane = l & 31;
    const int hi   = l >> 5;          // k-half selector within fragments
    const int n    = nt * 32 + lane;  // this lane's node (col in D)
    const int nc   = (n < 52) ? n : 0;  // clamped row for B-side reads
    const int samp = blockIdx.x * 4 + s;
    float* xsS = xs + s * 52 * STRF;

    // ---- closed-form GCN neighbors (self + 2 lateral(x2 dup) + <=2 chain) ----
    int nb[5]; float nw[5];
    {
        const int   fi = n >> 2, js = n & 3;
        const float dg = 5.f + (js > 0 ? 1.f : 0.f) + (js < 3 ? 1.f : 0.f);
        const float di = rsqrtf(dg);
        nb[0] = n;                          nw[0] = di * di;
        nb[1] = ((fi + 12) % 13) * 4 + js;  nw[1] = 2.f * di * di;
        nb[2] = ((fi + 1) % 13) * 4 + js;   nw[2] = 2.f * di * di;
        nb[3] = (js > 0) ? (n - 1) : 0;
        nw[3] = (js > 0) ? di * rsqrtf(6.f + (js > 1 ? 1.f : 0.f)) : 0.f;
        nb[4] = (js < 3) ? (n + 1) : 0;
        nw[4] = (js < 3) ? di * rsqrtf(6.f + (js < 2 ? 1.f : 0.f)) : 0.f;
        if (n >= 52) {
            #pragma unroll
            for (int c = 0; c < 5; ++c) { nb[c] = 0; nw[c] = 0.f; }
        }
    }

    float xf[4][16];   // x in D-frag layout: feature o = ot*32 + (r&3) + 8*(r>>2) + 4*hi

    // ---------------- encoder: x^T = relu(Win @ q^T + bin) ----------------
    {
        f32x4 z4; z4[0]=0.f; z4[1]=0.f; z4[2]=0.f; z4[3]=0.f;
        bf16x8 ah[4], am[4], al[4];
        #pragma unroll
        for (int ot = 0; ot < 4; ++ot) {
            f32x4 v0 = z4, v1 = z4;
            if (hi == 0) {  // k = 8*hi + e; only k<6 valid
                const int o_r = ot * 32 + lane;
                const f32x2 a = *(const f32x2*)(Win + o_r * 6);
                const f32x2 b = *(const f32x2*)(Win + o_r * 6 + 2);
                const f32x2 c = *(const f32x2*)(Win + o_r * 6 + 4);
                v0[0]=a[0]; v0[1]=a[1]; v0[2]=b[0]; v0[3]=b[1]; v1[0]=c[0]; v1[1]=c[1];
            }
            split8(v0, v1, ah[ot], am[ot], al[ot]);
        }
        f32x4 u0 = z4, u1 = z4;
        if (hi == 0 && n < 52) {
            const float* qp = q + (samp * 52 + n) * 6;
            const f32x2 a = *(const f32x2*)(qp);
            const f32x2 b = *(const f32x2*)(qp + 2);
            const f32x2 c = *(const f32x2*)(qp + 4);
            u0[0]=a[0]; u0[1]=a[1]; u0[2]=b[0]; u0[3]=b[1]; u1[0]=c[0]; u1[1]=c[1];
        }
        bf16x8 bh, bm, bl;
        split8(u0, u1, bh, bm, bl);

        #pragma unroll
        for (int ot = 0; ot < 4; ++ot) {
            f32x16 acc;
            #pragma unroll
            for (int r = 0; r < 16; ++r) acc[r] = 0.f;
            PASS6(acc, ah[ot], am[ot], al[ot], bh, bm, bl);
            #pragma unroll
            for (int j = 0; j < 4; ++j) {
                const f32x4 bv = *(const f32x4*)(bin + ot * 32 + 8 * j + 4 * hi);
                #pragma unroll
                for (int e = 0; e < 4; ++e)
                    xf[ot][4 * j + e] = fmaxf(acc[4 * j + e] + bv[e], 0.f);
            }
        }
    }

    auto writeMirror = [&]() {
        if (n < 52) {
            #pragma unroll
            for (int ot = 0; ot < 4; ++ot)
                #pragma unroll
                for (int j = 0; j < 4; ++j) {
                    f32x4 v = { xf[ot][4*j+0], xf[ot][4*j+1], xf[ot][4*j+2], xf[ot][4*j+3] };
                    *(f32x4*)&xsS[n * STRF + ot * 32 + 8 * j + 4 * hi] = v;
                }
        }
    };
    writeMirror();
    __syncthreads();

    // ------------- 3 GNN layers (L=0..2) + decoder-1 (L=3) -------------
    #pragma unroll 1
    for (int L = 0; L < 4; ++L) {
        // ---- gather t = A @ x (or copy x for L=3) into register cache ----
        f32x4 tc[8][2];
        #pragma unroll
        for (int kc = 0; kc < 8; ++kc) {
            const int kb = kc * 16 + 8 * hi;
            if (L < 3) {
                f32x4 a0, a1;
                #pragma unroll
                for (int e = 0; e < 4; ++e) { a0[e] = 0.f; a1[e] = 0.f; }
                #pragma unroll
                for (int c = 0; c < 5; ++c) {
                    const f32x4* xp = (const f32x4*)&xsS[nb[c] * STRF + kb];
                    a0 += nw[c] * xp[0];
                    a1 += nw[c] * xp[1];
                }
                tc[kc][0] = a0; tc[kc][1] = a1;
            } else {
                const f32x4* xp = (const f32x4*)&xsS[nc * STRF + kb];
                tc[kc][0] = xp[0]; tc[kc][1] = xp[1];
            }
        }

        const float* Wsrc = (L < 3) ? (Wg + L * 16384) : Wd1;
        const float* bsrc = (L < 3) ? (bg + L * 128)   : bd1;

        #pragma unroll
        for (int h = 0; h < 2; ++h) {
            // ---- stage 64 rows of W, 3-way split ----
            {
                const int lo = t >> 3;            // 0..63 local row
                const int k0 = (t & 7) * 16;      // 16 k's per thread
                const float* src = Wsrc + (h * 64 + lo) * 128 + k0;
                #pragma unroll
                for (int seg = 0; seg < 2; ++seg) {
                    const f32x4 v0 = *(const f32x4*)(src + seg * 8);
                    const f32x4 v1 = *(const f32x4*)(src + seg * 8 + 4);
                    bf16x8 hh, mm, ll;
                    split8(v0, v1, hh, mm, ll);
                    *(bf16x8*)&Wh[lo * STRW + k0 + seg * 8] = hh;
                    *(bf16x8*)&Wm[lo * STRW + k0 + seg * 8] = mm;
                    *(bf16x8*)&Wl[lo * STRW + k0 + seg * 8] = ll;
                }
            }
            __syncthreads();   // staged half visible (also: prev phase done reading)

            f32x16 acc2[2];
            #pragma unroll
            for (int oth = 0; oth < 2; ++oth)
                #pragma unroll
                for (int r = 0; r < 16; ++r) acc2[oth][r] = 0.f;

            #pragma unroll
            for (int kc = 0; kc < 8; ++kc) {
                bf16x8 bh, bm, bl;
                split8(tc[kc][0], tc[kc][1], bh, bm, bl);
                #pragma unroll
                for (int oth = 0; oth < 2; ++oth) {
                    const int ro = (oth * 32 + lane) * STRW + kc * 16 + 8 * hi;
                    const bf16x8 wh = *(const bf16x8*)&Wh[ro];
                    const bf16x8 wm = *(const bf16x8*)&Wm[ro];
                    const bf16x8 wl = *(const bf16x8*)&Wl[ro];
                    PASS6(acc2[oth], wh, wm, wl, bh, bm, bl);
                }
            }

            // ---- epilogue for this half's two ot tiles ----
            #pragma unroll
            for (int oth = 0; oth < 2; ++oth) {
                const int ot = 2 * h + oth;
                #pragma unroll
                for (int j = 0; j < 4; ++j) {
                    const f32x4 bv = *(const f32x4*)(bsrc + ot * 32 + 8 * j + 4 * hi);
                    #pragma unroll
                    for (int e = 0; e < 4; ++e) {
                        const float r = fmaxf(acc2[oth][4 * j + e] + bv[e], 0.f);
                        xf[ot][4 * j + e] = (L < 3) ? (xf[ot][4 * j + e] + r) : r;
                    }
                }
            }
            __syncthreads();   // before next half's staging overwrites W / end of layer
        }

        writeMirror();         // publish x_{L+1} (or y at L=3); gathers all done pre-stage
        __syncthreads();
    }

    // ---------------- decoder-2: out^T = Wd2 @ y^T + bd2 ----------------
    {
        f32x16 acc;
        #pragma unroll
        for (int r = 0; r < 16; ++r) acc[r] = 0.f;
        f32x4 z4; z4[0]=0.f; z4[1]=0.f; z4[2]=0.f; z4[3]=0.f;

        #pragma unroll
        for (int kc = 0; kc < 8; ++kc) {
            const int kb = kc * 16 + 8 * hi;
            const f32x4* xp = (const f32x4*)&xsS[nc * STRF + kb];
            bf16x8 bh, bm, bl;
            split8(xp[0], xp[1], bh, bm, bl);

            f32x4 w0 = z4, w1 = z4;
            if (lane < 6) {
                const f32x4* wp = (const f32x4*)(Wd2 + lane * 128 + kb);
                w0 = wp[0]; w1 = wp[1];
            }
            bf16x8 ah, am, al;
            split8(w0, w1, ah, am, al);
            PASS6(acc, ah, am, al, bh, bm, bl);
        }
        if (n < 52) {
            float* op = out + (samp * 52 + n) * 6;
            if (hi == 0) {
                #pragma unroll
                for (int r = 0; r < 4; ++r) op[r] = acc[r] + bd2[r];          // f = r
            } else {
                #pragma unroll
                for (int r = 0; r < 2; ++r) op[4 + r] = acc[r] + bd2[4 + r];  // f = 4+r
            }
        }
    }
}

extern "C" void kernel_launch(void* const* d_in, const int* in_sizes, int n_in,
                              void* d_out, int out_size, void* d_ws, size_t ws_size,
                              hipStream_t stream) {
    (void)in_sizes; (void)n_in; (void)d_ws; (void)ws_size; (void)out_size;
    const float* q   = (const float*)d_in[0];
    const float* Win = (const float*)d_in[1];
    const float* bin = (const float*)d_in[2];
    const float* Wg  = (const float*)d_in[3];
    const float* bg  = (const float*)d_in[4];
    const float* Wd1 = (const float*)d_in[5];
    const float* bd1 = (const float*)d_in[6];
    const float* Wd2 = (const float*)d_in[7];
    const float* bd2 = (const float*)d_in[8];
    float* out = (float*)d_out;
    mt_fwd<<<1024, 512, 0, stream>>>(q, Win, bin, Wg, bg, Wd1, bd1, Wd2, bd2, out);
}

// Round 4
// 157.400 us; speedup vs baseline: 1.4192x; 1.4192x over previous
//
#include <hip/hip_runtime.h>

// MicrotubuleDynamicsModel fused forward, round 4 structure:
//  - prep_w kernel: split Wg[0..2] and Wd1 into hi/lo bf16, packed in MFMA
//    A-fragment order into d_ws (L2-resident, read coalesced by main kernel).
//  - mt_fwd: 1 sample/block, 128 threads (2 waves = 2 node-halves).
//    LDS = 52x128 fp32 x-mirror only (26.6KB) -> 6 blocks/CU.
//    Per layer: gather t=A@x from LDS (closed-form adjacency), 2-split bf16
//    3-pass MFMA (v_mfma_f32_32x32x16_bf16), residual read-modify-write in LDS.

typedef __attribute__((ext_vector_type(2)))  float  f32x2;
typedef __attribute__((ext_vector_type(4)))  float  f32x4;
typedef __attribute__((ext_vector_type(16))) float  f32x16;
typedef __attribute__((ext_vector_type(8)))  __bf16 bf16x8;

#define MFMA(a, b, c) __builtin_amdgcn_mfma_f32_32x32x16_bf16((a), (b), (c), 0, 0, 0)

// xs swizzled index (dword units; kdw must be a multiple of 4)
__device__ __forceinline__ int xidx(int row, int kdw) {
    return row * 128 + (kdw ^ ((row & 7) << 2));
}

struct bfpair { __bf16 h, l; };
__device__ __forceinline__ bfpair splitf(float f) {
    bfpair p;
    p.h = (__bf16)f;               // RTN
    p.l = (__bf16)(f - (float)p.h);
    return p;
}

// ---------------- prep: split + fragment-pack W into workspace ----------------
// frag tid = (((L*8+kc)*4+ot)*2+hi)*32+lane ; elems = W[L][ot*32+lane][kc*16+hi*8+e]
__global__ __launch_bounds__(256) void prep_w(
    const float* __restrict__ Wg, const float* __restrict__ Wd1,
    __bf16* __restrict__ ws)
{
    const int tid  = blockIdx.x * 256 + threadIdx.x;   // 0..8191
    const int lane = tid & 31;
    const int hi   = (tid >> 5) & 1;
    const int ot   = (tid >> 6) & 3;
    const int kc   = (tid >> 8) & 7;
    const int L    = tid >> 11;
    const float* src = ((L < 3) ? (Wg + L * 16384) : Wd1)
                     + (ot * 32 + lane) * 128 + kc * 16 + hi * 8;
    const f32x4 v0 = *(const f32x4*)(src);
    const f32x4 v1 = *(const f32x4*)(src + 4);
    bf16x8 h8, l8;
    #pragma unroll
    for (int e = 0; e < 4; ++e) {
        bfpair p0 = splitf(v0[e]); h8[e]   = p0.h; l8[e]   = p0.l;
        bfpair p1 = splitf(v1[e]); h8[4+e] = p1.h; l8[4+e] = p1.l;
    }
    ((bf16x8*)ws)[tid]        = h8;   // Ph: 8192 frags * 16B = 131072 B
    ((bf16x8*)ws)[8192 + tid] = l8;   // Pl at +131072 B
}

// ------------------------------- main kernel -------------------------------
__global__ __launch_bounds__(128, 3) void mt_fwd(
    const float* __restrict__ q,   const float* __restrict__ Win, const float* __restrict__ bin,
    const float* __restrict__ bg,  const float* __restrict__ bd1,
    const float* __restrict__ Wd2, const float* __restrict__ bd2,
    const bf16x8* __restrict__ Ph, float* __restrict__ out)
{
    __shared__ __attribute__((aligned(16))) float xs[52 * 128];   // 26624 B

    const int t    = threadIdx.x;
    const int nt   = t >> 6;            // wave: node-tile 0/1
    const int l    = t & 63;
    const int lane = l & 31;
    const int hi   = l >> 5;
    const int n    = nt * 32 + lane;    // this lane's node (col in D)
    const int nc   = (n < 52) ? n : 0;
    const int samp = blockIdx.x;
    const bf16x8* Pl = Ph + 8192;

    // ---- closed-form GCN neighbors (self + 2 lateral(dup x2) + <=2 chain) ----
    int nb[5]; float nw[5];
    {
        const int   fi = n >> 2, js = n & 3;
        const float dg = 5.f + (js > 0 ? 1.f : 0.f) + (js < 3 ? 1.f : 0.f);
        const float di = rsqrtf(dg);
        nb[0] = n;                          nw[0] = di * di;
        nb[1] = ((fi + 12) % 13) * 4 + js;  nw[1] = 2.f * di * di;
        nb[2] = ((fi + 1) % 13) * 4 + js;   nw[2] = 2.f * di * di;
        nb[3] = (js > 0) ? (n - 1) : 0;
        nw[3] = (js > 0) ? di * rsqrtf(6.f + (js > 1 ? 1.f : 0.f)) : 0.f;
        nb[4] = (js < 3) ? (n + 1) : 0;
        nw[4] = (js < 3) ? di * rsqrtf(6.f + (js < 2 ? 1.f : 0.f)) : 0.f;
        if (n >= 52) {
            #pragma unroll
            for (int c = 0; c < 5; ++c) { nb[c] = 0; nw[c] = 0.f; }
        }
    }

    // ---------------- encoder: x^T = relu(Win @ q^T + bin) -> xs ----------------
    {
        f32x4 z4; z4[0]=0.f; z4[1]=0.f; z4[2]=0.f; z4[3]=0.f;
        f32x4 u0 = z4, u1 = z4;
        if (hi == 0 && n < 52) {
            const float* qp = q + (samp * 52 + n) * 6;
            const f32x2 a = *(const f32x2*)(qp);
            const f32x2 b = *(const f32x2*)(qp + 2);
            const f32x2 c = *(const f32x2*)(qp + 4);
            u0[0]=a[0]; u0[1]=a[1]; u0[2]=b[0]; u0[3]=b[1]; u1[0]=c[0]; u1[1]=c[1];
        }
        bf16x8 bh, bl;
        #pragma unroll
        for (int e = 0; e < 4; ++e) {
            bfpair p0 = splitf(u0[e]); bh[e]   = p0.h; bl[e]   = p0.l;
            bfpair p1 = splitf(u1[e]); bh[4+e] = p1.h; bl[4+e] = p1.l;
        }

        #pragma unroll
        for (int ot = 0; ot < 4; ++ot) {
            f32x4 v0 = z4, v1 = z4;
            if (hi == 0) {
                const int o_r = ot * 32 + lane;
                const f32x2 a = *(const f32x2*)(Win + o_r * 6);
                const f32x2 b = *(const f32x2*)(Win + o_r * 6 + 2);
                const f32x2 c = *(const f32x2*)(Win + o_r * 6 + 4);
                v0[0]=a[0]; v0[1]=a[1]; v0[2]=b[0]; v0[3]=b[1]; v1[0]=c[0]; v1[1]=c[1];
            }
            bf16x8 ah, al;
            #pragma unroll
            for (int e = 0; e < 4; ++e) {
                bfpair p0 = splitf(v0[e]); ah[e]   = p0.h; al[e]   = p0.l;
                bfpair p1 = splitf(v1[e]); ah[4+e] = p1.h; al[4+e] = p1.l;
            }
            f32x16 acc;
            #pragma unroll
            for (int r = 0; r < 16; ++r) acc[r] = 0.f;
            acc = MFMA(ah, bh, acc);
            acc = MFMA(ah, bl, acc);
            acc = MFMA(al, bh, acc);
            if (n < 52) {
                #pragma unroll
                for (int j = 0; j < 4; ++j) {
                    const f32x4 bv = *(const f32x4*)(bin + ot * 32 + 8 * j + 4 * hi);
                    f32x4 v;
                    #pragma unroll
                    for (int e = 0; e < 4; ++e) v[e] = fmaxf(acc[4 * j + e] + bv[e], 0.f);
                    *(f32x4*)&xs[xidx(n, ot * 32 + 8 * j + 4 * hi)] = v;
                }
            }
        }
    }

    // ------------- 3 GNN layers (L=0..2) + decoder-1 (L=3) -------------
    #pragma unroll 1
    for (int L = 0; L < 4; ++L) {
        __syncthreads();   // xs stable (previous epilogue writes visible)

        f32x16 acc[4];
        #pragma unroll
        for (int ot = 0; ot < 4; ++ot)
            #pragma unroll
            for (int r = 0; r < 16; ++r) acc[ot][r] = 0.f;

        const int fbase = (L * 8) * 256;   // frag index base for this layer

        #pragma unroll 1
        for (int kc = 0; kc < 8; ++kc) {
            const int kb = kc * 16 + 8 * hi;
            // B-fragment: t[n][kb..kb+7] (graph gather; plain x for decoder-1)
            f32x4 a0, a1;
            if (L < 3) {
                #pragma unroll
                for (int e = 0; e < 4; ++e) { a0[e] = 0.f; a1[e] = 0.f; }
                #pragma unroll
                for (int c = 0; c < 5; ++c) {
                    const f32x4 x0 = *(const f32x4*)&xs[xidx(nb[c], kb)];
                    const f32x4 x1 = *(const f32x4*)&xs[xidx(nb[c], kb + 4)];
                    a0 += nw[c] * x0;
                    a1 += nw[c] * x1;
                }
            } else {
                a0 = *(const f32x4*)&xs[xidx(nc, kb)];
                a1 = *(const f32x4*)&xs[xidx(nc, kb + 4)];
            }
            bf16x8 bh, bl;
            #pragma unroll
            for (int e = 0; e < 4; ++e) {
                bfpair p0 = splitf(a0[e]); bh[e]   = p0.h; bl[e]   = p0.l;
                bfpair p1 = splitf(a1[e]); bh[4+e] = p1.h; bl[4+e] = p1.l;
            }

            const int fk = fbase + kc * 256 + hi * 32 + lane;
            #pragma unroll
            for (int ot = 0; ot < 4; ++ot) {
                const bf16x8 wh = Ph[fk + ot * 64];
                const bf16x8 wl = Pl[fk + ot * 64];
                acc[ot] = MFMA(wh, bh, acc[ot]);
                acc[ot] = MFMA(wh, bl, acc[ot]);
                acc[ot] = MFMA(wl, bh, acc[ot]);
            }
        }

        __syncthreads();   // all xs reads of this layer done

        // epilogue: residual read-modify-write of own row (L<3); overwrite (L=3)
        const float* bsrc = (L < 3) ? (bg + L * 128) : bd1;
        if (n < 52) {
            #pragma unroll
            for (int ot = 0; ot < 4; ++ot)
                #pragma unroll
                for (int j = 0; j < 4; ++j) {
                    float* p = &xs[xidx(n, ot * 32 + 8 * j + 4 * hi)];
                    const f32x4 bv = *(const f32x4*)(bsrc + ot * 32 + 8 * j + 4 * hi);
                    f32x4 v;
                    if (L < 3) {
                        const f32x4 cur = *(const f32x4*)p;
                        #pragma unroll
                        for (int e = 0; e < 4; ++e)
                            v[e] = cur[e] + fmaxf(acc[ot][4 * j + e] + bv[e], 0.f);
                    } else {
                        #pragma unroll
                        for (int e = 0; e < 4; ++e)
                            v[e] = fmaxf(acc[ot][4 * j + e] + bv[e], 0.f);
                    }
                    *(f32x4*)p = v;
                }
        }
    }
    __syncthreads();

    // ---------------- decoder-2: out^T = Wd2 @ y^T + bd2 ----------------
    {
        f32x16 acc;
        #pragma unroll
        for (int r = 0; r < 16; ++r) acc[r] = 0.f;
        f32x4 z4; z4[0]=0.f; z4[1]=0.f; z4[2]=0.f; z4[3]=0.f;

        #pragma unroll 1
        for (int kc = 0; kc < 8; ++kc) {
            const int kb = kc * 16 + 8 * hi;
            const f32x4 a0 = *(const f32x4*)&xs[xidx(nc, kb)];
            const f32x4 a1 = *(const f32x4*)&xs[xidx(nc, kb + 4)];
            bf16x8 bh, bl;
            #pragma unroll
            for (int e = 0; e < 4; ++e) {
                bfpair p0 = splitf(a0[e]); bh[e]   = p0.h; bl[e]   = p0.l;
                bfpair p1 = splitf(a1[e]); bh[4+e] = p1.h; bl[4+e] = p1.l;
            }
            f32x4 w0 = z4, w1 = z4;
            if (lane < 6) {
                const float* wp = Wd2 + lane * 128 + kb;
                w0 = *(const f32x4*)(wp);
                w1 = *(const f32x4*)(wp + 4);
            }
            bf16x8 ah, al;
            #pragma unroll
            for (int e = 0; e < 4; ++e) {
                bfpair p0 = splitf(w0[e]); ah[e]   = p0.h; al[e]   = p0.l;
                bfpair p1 = splitf(w1[e]); ah[4+e] = p1.h; al[4+e] = p1.l;
            }
            acc = MFMA(ah, bh, acc);
            acc = MFMA(ah, bl, acc);
            acc = MFMA(al, bh, acc);
        }
        if (n < 52) {
            float* op = out + (samp * 52 + n) * 6;
            if (hi == 0) {
                #pragma unroll
                for (int r = 0; r < 4; ++r) op[r] = acc[r] + bd2[r];          // f = r
            } else {
                #pragma unroll
                for (int r = 0; r < 2; ++r) op[4 + r] = acc[r] + bd2[4 + r];  // f = 4+r
            }
        }
    }
}

extern "C" void kernel_launch(void* const* d_in, const int* in_sizes, int n_in,
                              void* d_out, int out_size, void* d_ws, size_t ws_size,
                              hipStream_t stream) {
    (void)in_sizes; (void)n_in; (void)ws_size; (void)out_size;
    const float* q   = (const float*)d_in[0];
    const float* Win = (const float*)d_in[1];
    const float* bin = (const float*)d_in[2];
    const float* Wg  = (const float*)d_in[3];
    const float* bg  = (const float*)d_in[4];
    const float* Wd1 = (const float*)d_in[5];
    const float* bd1 = (const float*)d_in[6];
    const float* Wd2 = (const float*)d_in[7];
    const float* bd2 = (const float*)d_in[8];
    float* out = (float*)d_out;

    prep_w<<<32, 256, 0, stream>>>(Wg, Wd1, (__bf16*)d_ws);
    mt_fwd<<<4096, 128, 0, stream>>>(q, Win, bin, bg, bd1, Wd2, bd2,
                                     (const bf16x8*)d_ws, out);
}